// Round 2
// baseline (743.744 us; speedup 1.0000x reference)
//
#include <hip/hip_runtime.h>
#include <hip/hip_bf16.h>

// ---------------------------------------------------------------------------
// Attention block, MI355X bf16-MFMA (round 2: conflict-free fragment-
// sequential LDS layout + strength-reduced staging addresses in gemm_nt).
// Shapes (hardcoded from setup_inputs): B=4 S=512 D=4096 H=32 HKV=8 HD=128
// START=512 T=1024, M=B*S=2048, NQKV=H*HD+2*HKV*HD=6144.
// ---------------------------------------------------------------------------

#define B_ 4
#define S_ 512
#define D_ 4096
#define H_ 32
#define HKV_ 8
#define HD_ 128
#define T_ 1024
#define M_ 2048
#define NQKV_ 6144

typedef __attribute__((ext_vector_type(8))) short bf16x8;  // 8 bf16 (4 VGPRs)
typedef __attribute__((ext_vector_type(4))) float f32x4;   // MFMA C/D

#define GLOAD_LDS16(g, l)                                                     \
  __builtin_amdgcn_global_load_lds(                                           \
      (const __attribute__((address_space(1))) void*)(g),                     \
      (__attribute__((address_space(3))) void*)(l), 16, 0, 0)

__device__ __forceinline__ void st_c(float* p, float v) { *p = v; }
__device__ __forceinline__ void st_c(__hip_bfloat16* p, float v) {
  *p = __float2bfloat16(v);
}
__device__ __forceinline__ float ld_f(const float* p) { return *p; }
__device__ __forceinline__ float ld_f(const __hip_bfloat16* p) {
  return __bfloat162float(*p);
}

// ---------------------------------------------------------------------------
// fp32 -> bf16 convert (vectorized float4 -> 4x bf16 packed 8B store)
// ---------------------------------------------------------------------------
__global__ void cvt_f32_bf16(const float* __restrict__ in,
                             __hip_bfloat16* __restrict__ out, long n) {
  long i = ((long)blockIdx.x * blockDim.x + threadIdx.x) * 4;
  if (i >= n) return;
  float4 v = *(const float4*)(in + i);
  __hip_bfloat16 t[4] = {__float2bfloat16(v.x), __float2bfloat16(v.y),
                         __float2bfloat16(v.z), __float2bfloat16(v.w)};
  *(uint2*)(out + i) = *(const uint2*)t;
}

// ---------------------------------------------------------------------------
// NT bf16 MFMA GEMM: C[m][n] = sum_k A[m][k]*B[n][k]; both operands K-contig.
// 128x128 tile, BK=32, 4 waves (2x2 of 64x64), mfma_f32_16x16x32_bf16.
//
// LDS layout (round 2): fragment-sequential. Block bi in [0,8) holds tile
// rows [16bi, 16bi+16) x 32 k in one contiguous 1024B chunk; lane l's 16B
// fragment slice lives at byte bi*1024 + l*16 = (row 16bi+(l&15),
// k-chunk (l>>4)*8). Staging permutes the GLOBAL source per lane (LDS dest
// of global_load_lds is fixed at wave-uniform base + lane*16), so every
// fragment ds_read_b128 is a sequential 1024B wave access -> conflict-free.
// Round-0 row-major layout had 8-way bank conflicts (SQ_LDS_BANK_CONFLICT
// = 1.26e7/dispatch); global coalescing is unchanged (same 64B segments).
//
// Batch: z -> (b = z/Hdiv, h = z%Hdiv); A += b*sAb + h*sAh;
//        B += b*sBb + (h/rep)*sBh; C += b*sCb + h*sCh.
// Requires M%128==0, N%128==0, K%32==0 (true for all uses here).
// ---------------------------------------------------------------------------
template <typename CT>
__global__ __launch_bounds__(256) void gemm_nt(
    const __hip_bfloat16* __restrict__ A, const __hip_bfloat16* __restrict__ B,
    CT* __restrict__ C, int M, int N, int K, long ldA, long ldB, long ldC,
    int Hdiv, int rep, long sAb, long sAh, long sBb, long sBh, long sCb,
    long sCh) {
  int z = blockIdx.z;
  int zb = z / Hdiv, zh = z - zb * Hdiv;
  A += (long)zb * sAb + (long)zh * sAh;
  B += (long)zb * sBb + (long)(zh / rep) * sBh;
  C += (long)zb * sCb + (long)zh * sCh;

  const int m0 = blockIdx.y * 128;
  const int n0 = blockIdx.x * 128;
  const int tid = threadIdx.x;
  const int wave = tid >> 6, lane = tid & 63;
  const int wm = (wave >> 1) * 64, wn = (wave & 1) * 64;

  __shared__ __align__(16) __hip_bfloat16 As[128 * 32];
  __shared__ __align__(16) __hip_bfloat16 Bs[128 * 32];

  // staging: wave w fills blocks w and w+4 of each tile; lane l supplies
  // row 16*blk + (l&15), k-chunk (l>>4)*8. Pointers hoisted, +32 elems/iter.
  const int lr = lane & 15, lc = (lane >> 4) * 8;
  const __hip_bfloat16* gA0 = A + (long)(m0 + wave * 16 + lr) * ldA + lc;
  const __hip_bfloat16* gA1 = A + (long)(m0 + (wave + 4) * 16 + lr) * ldA + lc;
  const __hip_bfloat16* gB0 = B + (long)(n0 + wave * 16 + lr) * ldB + lc;
  const __hip_bfloat16* gB1 = B + (long)(n0 + (wave + 4) * 16 + lr) * ldB + lc;
  __hip_bfloat16* sA0 = &As[wave * 512];        // byte base wave*1024
  __hip_bfloat16* sA1 = &As[(wave + 4) * 512];
  __hip_bfloat16* sB0 = &Bs[wave * 512];
  __hip_bfloat16* sB1 = &Bs[(wave + 4) * 512];

  // fragment read bases (element offsets; ds_read = base + imm)
  const int abase = (wm >> 4) * 512 + lane * 8;
  const int bbase = (wn >> 4) * 512 + lane * 8;

  f32x4 acc[4][4];
#pragma unroll
  for (int i = 0; i < 4; i++)
#pragma unroll
    for (int j = 0; j < 4; j++) acc[i][j] = f32x4{0.f, 0.f, 0.f, 0.f};

  for (int kt = 0; kt < K; kt += 32) {
    GLOAD_LDS16(gA0, sA0);
    GLOAD_LDS16(gA1, sA1);
    GLOAD_LDS16(gB0, sB0);
    GLOAD_LDS16(gB1, sB1);
    gA0 += 32;
    gA1 += 32;
    gB0 += 32;
    gB1 += 32;
    __syncthreads();  // drains vmcnt: LDS tiles ready

    bf16x8 af[4], bfv[4];
#pragma unroll
    for (int i = 0; i < 4; i++) {
      af[i] = *(const bf16x8*)&As[abase + i * 512];
      bfv[i] = *(const bf16x8*)&Bs[bbase + i * 512];
    }
#pragma unroll
    for (int i = 0; i < 4; i++)
#pragma unroll
      for (int j = 0; j < 4; j++)
        acc[i][j] =
            __builtin_amdgcn_mfma_f32_16x16x32_bf16(af[i], bfv[j], acc[i][j],
                                                    0, 0, 0);
    __syncthreads();  // all waves done reading before next stage overwrites
  }

  // epilogue: C/D map col = lane&15, row = (lane>>4)*4 + r  [measured m89/m91]
  const int crow0 = m0 + wm + (lane >> 4) * 4;
  const int ccol0 = n0 + wn + (lane & 15);
#pragma unroll
  for (int i = 0; i < 4; i++)
#pragma unroll
    for (int j = 0; j < 4; j++)
#pragma unroll
      for (int r = 0; r < 4; r++)
        st_c(&C[(long)(crow0 + i * 16 + r) * ldC + (ccol0 + j * 16)],
             acc[i][j][r]);
}

// ---------------------------------------------------------------------------
// RoPE on Q and K-new (reads fp32 qkv, writes bf16 q (b,s,h,d) and bf16 K-new
// into assembled K (b,kvh,512+s,d)). Interleaved pairs (2i, 2i+1).
// grid (10, 2048) x 256: j in [0,2560): j<2048 -> Q pair, else K pair.
// ---------------------------------------------------------------------------
__global__ void rope_kernel(const float* __restrict__ qkv,
                            const float* __restrict__ fcos,
                            const float* __restrict__ fsin,
                            __hip_bfloat16* __restrict__ qb,
                            __hip_bfloat16* __restrict__ kb) {
  int m = blockIdx.y;                                  // 0..2047 (b*S+s)
  int j = blockIdx.x * blockDim.x + threadIdx.x;       // pair index
  if (j >= 2560) return;
  int s = m & (S_ - 1);
  long rowbase = (long)m * NQKV_;
  if (j < 2048) {  // Q: element pair (2j, 2j+1) in [0,4096)
    int dpair = j & 63;
    float a = qkv[rowbase + 2 * j], bb = qkv[rowbase + 2 * j + 1];
    float c = fcos[s * 64 + dpair], si = fsin[s * 64 + dpair];
    long o = (long)m * 4096 + 2 * j;
    qb[o] = __float2bfloat16(a * c - bb * si);
    qb[o + 1] = __float2bfloat16(a * si + bb * c);
  } else {  // K: pair (4096+2j2, ...)
    int j2 = j - 2048;  // 0..511
    int kvh = j2 >> 6, dpair = j2 & 63;
    float a = qkv[rowbase + 4096 + 2 * j2], bb = qkv[rowbase + 4096 + 2 * j2 + 1];
    float c = fcos[s * 64 + dpair], si = fsin[s * 64 + dpair];
    int b = m >> 9;
    long o = (((long)(b * HKV_ + kvh)) * T_ + 512 + s) * HD_ + 2 * dpair;
    kb[o] = __float2bfloat16(a * c - bb * si);
    kb[o + 1] = __float2bfloat16(a * si + bb * c);
  }
}

// K cache part: kb[b][kvh][t][d] = bf16(cache_k[b][t][kvh][d]), t<512.
__global__ void kcache_cvt(const float* __restrict__ cache_k,
                           __hip_bfloat16* __restrict__ kb) {
  long i = (long)blockIdx.x * 256 + threadIdx.x;  // over 4*8*512*128
  if (i >= (long)B_ * HKV_ * 512 * HD_) return;
  int d = i & 127;
  int t = (i >> 7) & 511;
  int kvh = (i >> 16) & 7;
  int b = i >> 19;
  long o = (((long)(b * HKV_ + kvh)) * T_ + t) * HD_ + d;
  kb[o] = __float2bfloat16(
      cache_k[(((long)(b * 512 + t)) * HKV_ + kvh) * HD_ + d]);
}

// V assemble+transpose: vtb[b][kvh][d][t] <- cache_v (t<512) / qkv xv (t>=512).
// LDS 32x32 tile transpose for coalescing both sides. grid (32,4,32) x (32,8).
__global__ void v_transpose(const float* __restrict__ cache_v,
                            const float* __restrict__ qkv,
                            __hip_bfloat16* __restrict__ vtb) {
  __shared__ float tile[32][33];
  int t0 = blockIdx.x * 32, d0 = blockIdx.y * 32;
  int bk = blockIdx.z;
  int b = bk >> 3, kvh = bk & 7;
#pragma unroll
  for (int it = 0; it < 4; it++) {
    int t = t0 + threadIdx.y + it * 8;
    int d = d0 + threadIdx.x;
    float v;
    if (t < 512)
      v = cache_v[(((long)(b * 512 + t)) * HKV_ + kvh) * HD_ + d];
    else
      v = qkv[((long)(b * S_) + (t - 512)) * NQKV_ + 5120 + kvh * HD_ + d];
    tile[threadIdx.y + it * 8][threadIdx.x] = v;
  }
  __syncthreads();
#pragma unroll
  for (int it = 0; it < 4; it++) {
    int d = d0 + threadIdx.y + it * 8;
    int t = t0 + threadIdx.x;
    vtb[((long)bk * HD_ + d) * T_ + t] =
        __float2bfloat16(tile[threadIdx.x][threadIdx.y + it * 8]);
  }
}

// ---------------------------------------------------------------------------
// Masked softmax over score rows. One block (256 thr) per (z,q) row of T=1024.
// Valid length L = 513+q (causal, START=512). Writes bf16 P in-place over the
// score row (P row overlays the first 2KB of its own S row => race-free).
// ---------------------------------------------------------------------------
template <typename SDT>
__global__ void softmax_kernel(SDT* __restrict__ Sb,
                               __hip_bfloat16* __restrict__ Pb, long ldS,
                               long ldP) {
  int q = blockIdx.x, z = blockIdx.y;
  long srow = ((long)z * S_ + q) * ldS;
  long prow = ((long)z * S_ + q) * ldP;
  int tid = threadIdx.x;
  int L = 513 + q;
  const float scale = 0.08838834764831845f;  // 1/sqrt(128)

  float v[4];
  float m = -1e30f;
#pragma unroll
  for (int i = 0; i < 4; i++) {
    int k = tid + i * 256;
    float s = (k < L) ? ld_f(&Sb[srow + k]) * scale : -1e30f;
    v[i] = s;
    m = fmaxf(m, s);
  }
#pragma unroll
  for (int off = 32; off; off >>= 1) m = fmaxf(m, __shfl_xor(m, off));
  __shared__ float redm[4], reds[4];
  int wid = tid >> 6;
  if ((tid & 63) == 0) redm[wid] = m;
  __syncthreads();  // also: all S reads complete before in-place P writes
  m = fmaxf(fmaxf(redm[0], redm[1]), fmaxf(redm[2], redm[3]));

  float sum = 0.f, p[4];
#pragma unroll
  for (int i = 0; i < 4; i++) {
    int k = tid + i * 256;
    p[i] = (k < L) ? __expf(v[i] - m) : 0.f;
    sum += p[i];
  }
#pragma unroll
  for (int off = 32; off; off >>= 1) sum += __shfl_xor(sum, off);
  if ((tid & 63) == 0) reds[wid] = sum;
  __syncthreads();
  sum = reds[0] + reds[1] + reds[2] + reds[3];
  float inv = 1.f / sum;
#pragma unroll
  for (int i = 0; i < 4; i++) {
    int k = tid + i * 256;
    Pb[prow + k] = __float2bfloat16(p[i] * inv);
  }
}

// ---------------------------------------------------------------------------
extern "C" void kernel_launch(void* const* d_in, const int* in_sizes, int n_in,
                              void* d_out, int out_size, void* d_ws,
                              size_t ws_size, hipStream_t stream) {
  const float* x = (const float*)d_in[0];
  const float* wq = (const float*)d_in[1];
  const float* wk = (const float*)d_in[2];
  const float* wv = (const float*)d_in[3];
  const float* wo = (const float*)d_in[4];
  const float* fcos = (const float*)d_in[5];
  const float* fsin = (const float*)d_in[6];
  const float* cache_k = (const float*)d_in[7];
  const float* cache_v = (const float*)d_in[8];
  float* out = (float*)d_out;

  // ---- workspace layout (phase-aliased; stream order guarantees safety) ----
  // R0: xb (QKV-GEMM A) -> qb (rope'd Q) -> ob (attn out), all 16.8MB bf16
  // R1: wqkv bf16 (50.3MB) -> wo bf16 (33.6MB)
  // R2: qkv fp32 (50.3MB) -> scores S (268.4MB fp32 or 134.2MB bf16; P bf16
  //     packed in-place over S rows)
  // R3: kb  bf16 (b,kvh,t,d)   8.4MB
  // R4: vtb bf16 (b,kvh,d,t)   8.4MB
  char* ws = (char*)d_ws;
  const size_t szR0 = (size_t)M_ * 4096 * 2;
  const size_t szR1 = (size_t)NQKV_ * D_ * 2;
  const size_t szS_f32 = (size_t)B_ * H_ * S_ * T_ * 4;
  const size_t szKV = (size_t)B_ * HKV_ * T_ * HD_ * 2;
  const size_t base = szR0 + szR1 + 2 * szKV;
  bool sf32 = (ws_size >= base + szS_f32 + 1024);
  const size_t szR2 = sf32 ? szS_f32 : szS_f32 / 2;

  size_t R0 = 0;
  size_t R1 = R0 + szR0;
  size_t R2 = R1 + szR1;
  size_t R3 = R2 + szR2;
  size_t R4 = R3 + szKV;

  __hip_bfloat16* xb = (__hip_bfloat16*)(ws + R0);   // also qb, ob
  __hip_bfloat16* wqkvb = (__hip_bfloat16*)(ws + R1);  // also wob
  float* qkvf = (float*)(ws + R2);
  __hip_bfloat16* kb = (__hip_bfloat16*)(ws + R3);
  __hip_bfloat16* vtb = (__hip_bfloat16*)(ws + R4);

  dim3 blk(256);

  // 1) converts: x, wq|wk|wv -> bf16
  cvt_f32_bf16<<<(M_ * (long)D_ / 4 + 255) / 256, blk, 0, stream>>>(
      x, xb, (long)M_ * D_);
  cvt_f32_bf16<<<((long)D_ * D_ / 4 + 255) / 256, blk, 0, stream>>>(
      wq, wqkvb, (long)D_ * D_);
  cvt_f32_bf16<<<((long)1024 * D_ / 4 + 255) / 256, blk, 0, stream>>>(
      wk, wqkvb + (long)4096 * D_, (long)1024 * D_);
  cvt_f32_bf16<<<((long)1024 * D_ / 4 + 255) / 256, blk, 0, stream>>>(
      wv, wqkvb + (long)5120 * D_, (long)1024 * D_);

  // 2) QKV projection: qkvf[m][e] = sum_d xb[m][d] * wqkv[e][d]
  gemm_nt<float><<<dim3(NQKV_ / 128, M_ / 128, 1), blk, 0, stream>>>(
      xb, wqkvb, qkvf, M_, NQKV_, D_, D_, D_, NQKV_, 1, 1, 0, 0, 0, 0, 0, 0);

  // 3) RoPE -> qb (reuses R0; xb dead), K-new into kb
  __hip_bfloat16* qb = xb;
  rope_kernel<<<dim3(10, M_), blk, 0, stream>>>(qkvf, fcos, fsin, qb, kb);

  // 4) K cache convert, V assemble+transpose
  kcache_cvt<<<((long)B_ * HKV_ * 512 * HD_ + 255) / 256, blk, 0, stream>>>(
      cache_k, kb);
  v_transpose<<<dim3(T_ / 32, HD_ / 32, B_ * HKV_), dim3(32, 8), 0, stream>>>(
      cache_v, qkvf, vtb);

  // 5) wo -> bf16 (R1; wqkv dead after step 2, stream-ordered)
  __hip_bfloat16* wob = wqkvb;
  cvt_f32_bf16<<<((long)D_ * D_ / 4 + 255) / 256, blk, 0, stream>>>(
      wo, wob, (long)D_ * D_);

  // 6) scores: S[z][q][k] = sum_d Q[b,q,h,d] * K[b,kvh,k,d]; z=b*H+h
  long ldP = sf32 ? 2 * T_ : T_;
  if (sf32) {
    gemm_nt<float><<<dim3(T_ / 128, S_ / 128, B_ * H_), blk, 0, stream>>>(
        qb, kb, (float*)(ws + R2), S_, T_, HD_, (long)H_ * HD_, HD_, T_, H_, 4,
        (long)S_ * H_ * HD_, HD_, (long)HKV_ * T_ * HD_, (long)T_ * HD_,
        (long)H_ * S_ * T_, (long)S_ * T_);
    softmax_kernel<float><<<dim3(S_, B_ * H_), blk, 0, stream>>>(
        (float*)(ws + R2), (__hip_bfloat16*)(ws + R2), T_, ldP);
  } else {
    gemm_nt<__hip_bfloat16>
        <<<dim3(T_ / 128, S_ / 128, B_ * H_), blk, 0, stream>>>(
            qb, kb, (__hip_bfloat16*)(ws + R2), S_, T_, HD_, (long)H_ * HD_,
            HD_, T_, H_, 4, (long)S_ * H_ * HD_, HD_, (long)HKV_ * T_ * HD_,
            (long)T_ * HD_, (long)H_ * S_ * T_, (long)S_ * T_);
    softmax_kernel<__hip_bfloat16><<<dim3(S_, B_ * H_), blk, 0, stream>>>(
        (__hip_bfloat16*)(ws + R2), (__hip_bfloat16*)(ws + R2), T_, ldP);
  }

  // 7) PV: ob[b,q,h,d] = sum_k P[z][q][k] * VT[b,kvh,d,k]  (R0; qb dead)
  __hip_bfloat16* ob = xb;
  gemm_nt<__hip_bfloat16><<<dim3(HD_ / 128, S_ / 128, B_ * H_), blk, 0,
                            stream>>>(
      (const __hip_bfloat16*)(ws + R2), vtb, ob, S_, HD_, T_, ldP, T_,
      (long)H_ * HD_, H_, 4, (long)H_ * S_ * ldP, (long)S_ * ldP,
      (long)HKV_ * HD_ * T_, (long)HD_ * T_, (long)S_ * H_ * HD_, (long)HD_);

  // 8) output projection: out[m][d] = sum_e ob[m][e] * wo[d][e]
  gemm_nt<float><<<dim3(D_ / 128, M_ / 128, 1), blk, 0, stream>>>(
      ob, wob, out, M_, D_, D_, D_, D_, D_, 1, 1, 0, 0, 0, 0, 0, 0);
}

// Round 3
// 655.186 us; speedup vs baseline: 1.1352x; 1.1352x over previous
//
#include <hip/hip_runtime.h>
#include <hip/hip_bf16.h>

// ---------------------------------------------------------------------------
// Attention block, MI355X bf16-MFMA (round 3: XOR-chunk-swizzled LDS layout —
// conflict-free ds_read AND quad-contiguous global staging).
// Shapes (hardcoded from setup_inputs): B=4 S=512 D=4096 H=32 HKV=8 HD=128
// START=512 T=1024, M=B*S=2048, NQKV=H*HD+2*HKV*HD=6144.
// ---------------------------------------------------------------------------

#define B_ 4
#define S_ 512
#define D_ 4096
#define H_ 32
#define HKV_ 8
#define HD_ 128
#define T_ 1024
#define M_ 2048
#define NQKV_ 6144

typedef __attribute__((ext_vector_type(8))) short bf16x8;  // 8 bf16 (4 VGPRs)
typedef __attribute__((ext_vector_type(4))) float f32x4;   // MFMA C/D

#define GLOAD_LDS16(g, l)                                                     \
  __builtin_amdgcn_global_load_lds(                                           \
      (const __attribute__((address_space(1))) void*)(g),                     \
      (__attribute__((address_space(3))) void*)(l), 16, 0, 0)

__device__ __forceinline__ void st_c(float* p, float v) { *p = v; }
__device__ __forceinline__ void st_c(__hip_bfloat16* p, float v) {
  *p = __float2bfloat16(v);
}
__device__ __forceinline__ float ld_f(const float* p) { return *p; }
__device__ __forceinline__ float ld_f(const __hip_bfloat16* p) {
  return __bfloat162float(*p);
}

// ---------------------------------------------------------------------------
// fp32 -> bf16 convert (vectorized float4 -> 4x bf16 packed 8B store)
// ---------------------------------------------------------------------------
__global__ void cvt_f32_bf16(const float* __restrict__ in,
                             __hip_bfloat16* __restrict__ out, long n) {
  long i = ((long)blockIdx.x * blockDim.x + threadIdx.x) * 4;
  if (i >= n) return;
  float4 v = *(const float4*)(in + i);
  __hip_bfloat16 t[4] = {__float2bfloat16(v.x), __float2bfloat16(v.y),
                         __float2bfloat16(v.z), __float2bfloat16(v.w)};
  *(uint2*)(out + i) = *(const uint2*)t;
}

// ---------------------------------------------------------------------------
// NT bf16 MFMA GEMM: C[m][n] = sum_k A[m][k]*B[n][k]; both operands K-contig.
// 128x128 tile, BK=32, 4 waves (2x2 of 64x64), mfma_f32_16x16x32_bf16.
//
// LDS layout (round 3): XOR-chunk swizzle. Tile row r occupies bytes
// [r*64, r*64+64); slot s in [0,4) of that row holds global 16B k-chunk
// c = s ^ ((r>>1)&3).
//  - Staging (round-0 slot order): thread handling slot 4r+s reads global
//    chunk c of row r -> each 4-lane quad covers ONE aligned 64B segment
//    with lane-ADJACENT addresses (TA merges; round-2's stride-16 lanes
//    defeated the merge window and cost 28% on the QKV GEMM).
//  - Fragment ds_read_b128: lane l reads slot s = (l>>4) ^ (((l&15)>>1)&3);
//    bank-group (4*(l&15) + s) mod 8 covers each group exactly twice per
//    16-lane phase -> 2-way aliasing = free (m136). Round-0 row-major had
//    8-way (1.26e7 conflict cycles/dispatch).
//
// Batch: z -> (b = z/Hdiv, h = z%Hdiv); A += b*sAb + h*sAh;
//        B += b*sBb + (h/rep)*sBh; C += b*sCb + h*sCh.
// Requires M%128==0, N%128==0, K%32==0 (true for all uses here).
// ---------------------------------------------------------------------------
template <typename CT>
__global__ __launch_bounds__(256) void gemm_nt(
    const __hip_bfloat16* __restrict__ A, const __hip_bfloat16* __restrict__ B,
    CT* __restrict__ C, int M, int N, int K, long ldA, long ldB, long ldC,
    int Hdiv, int rep, long sAb, long sAh, long sBb, long sBh, long sCb,
    long sCh) {
  int z = blockIdx.z;
  int zb = z / Hdiv, zh = z - zb * Hdiv;
  A += (long)zb * sAb + (long)zh * sAh;
  B += (long)zb * sBb + (long)(zh / rep) * sBh;
  C += (long)zb * sCb + (long)zh * sCh;

  const int m0 = blockIdx.y * 128;
  const int n0 = blockIdx.x * 128;
  const int tid = threadIdx.x;
  const int wave = tid >> 6, lane = tid & 63;
  const int wm = (wave >> 1) * 64, wn = (wave & 1) * 64;

  __shared__ __align__(16) __hip_bfloat16 As[128 * 32];
  __shared__ __align__(16) __hip_bfloat16 Bs[128 * 32];

  // staging: slot = it*256 + tid; row = slot>>2, s = slot&3,
  // global chunk c = s ^ ((row>>1)&3). Pointers hoisted, +32 elems/iter.
  const int slot0 = tid, slot1 = 256 + tid;
  const int r0 = slot0 >> 2, c0 = (slot0 & 3) ^ ((r0 >> 1) & 3);
  const int r1 = slot1 >> 2, c1 = (slot1 & 3) ^ ((r1 >> 1) & 3);
  const __hip_bfloat16* gA0 = A + (long)(m0 + r0) * ldA + c0 * 8;
  const __hip_bfloat16* gA1 = A + (long)(m0 + r1) * ldA + c1 * 8;
  const __hip_bfloat16* gB0 = B + (long)(n0 + r0) * ldB + c0 * 8;
  const __hip_bfloat16* gB1 = B + (long)(n0 + r1) * ldB + c1 * 8;
  // LDS dest is wave-uniform base + lane*16 (HW); elem offsets:
  __hip_bfloat16* sA0 = &As[wave * 512];
  __hip_bfloat16* sA1 = &As[2048 + wave * 512];
  __hip_bfloat16* sB0 = &Bs[wave * 512];
  __hip_bfloat16* sB1 = &Bs[2048 + wave * 512];

  // fragment read: lane l -> tile row wm + i*16 + (l&15), swizzled slot
  // s = (l>>4) ^ (((l&15)>>1)&3)  (i- and wave-independent). elem addr =
  // row*32 + s*8 = abase + i*512.
  const int lr = lane & 15;
  const int sfrag = (lane >> 4) ^ ((lr >> 1) & 3);
  const int abase = (wm + lr) * 32 + sfrag * 8;
  const int bbase = (wn + lr) * 32 + sfrag * 8;

  f32x4 acc[4][4];
#pragma unroll
  for (int i = 0; i < 4; i++)
#pragma unroll
    for (int j = 0; j < 4; j++) acc[i][j] = f32x4{0.f, 0.f, 0.f, 0.f};

  for (int kt = 0; kt < K; kt += 32) {
    GLOAD_LDS16(gA0, sA0);
    GLOAD_LDS16(gA1, sA1);
    GLOAD_LDS16(gB0, sB0);
    GLOAD_LDS16(gB1, sB1);
    gA0 += 32;
    gA1 += 32;
    gB0 += 32;
    gB1 += 32;
    __syncthreads();  // drains vmcnt: LDS tiles ready

    bf16x8 af[4], bfv[4];
#pragma unroll
    for (int i = 0; i < 4; i++) {
      af[i] = *(const bf16x8*)&As[abase + i * 512];
      bfv[i] = *(const bf16x8*)&Bs[bbase + i * 512];
    }
#pragma unroll
    for (int i = 0; i < 4; i++)
#pragma unroll
      for (int j = 0; j < 4; j++)
        acc[i][j] =
            __builtin_amdgcn_mfma_f32_16x16x32_bf16(af[i], bfv[j], acc[i][j],
                                                    0, 0, 0);
    __syncthreads();  // all waves done reading before next stage overwrites
  }

  // epilogue: C/D map col = lane&15, row = (lane>>4)*4 + r  [measured m89/m91]
  const int crow0 = m0 + wm + (lane >> 4) * 4;
  const int ccol0 = n0 + wn + (lane & 15);
#pragma unroll
  for (int i = 0; i < 4; i++)
#pragma unroll
    for (int j = 0; j < 4; j++)
#pragma unroll
      for (int r = 0; r < 4; r++)
        st_c(&C[(long)(crow0 + i * 16 + r) * ldC + (ccol0 + j * 16)],
             acc[i][j][r]);
}

// ---------------------------------------------------------------------------
// RoPE on Q and K-new (reads fp32 qkv, writes bf16 q (b,s,h,d) and bf16 K-new
// into assembled K (b,kvh,512+s,d)). Interleaved pairs (2i, 2i+1).
// grid (10, 2048) x 256: j in [0,2560): j<2048 -> Q pair, else K pair.
// ---------------------------------------------------------------------------
__global__ void rope_kernel(const float* __restrict__ qkv,
                            const float* __restrict__ fcos,
                            const float* __restrict__ fsin,
                            __hip_bfloat16* __restrict__ qb,
                            __hip_bfloat16* __restrict__ kb) {
  int m = blockIdx.y;                                  // 0..2047 (b*S+s)
  int j = blockIdx.x * blockDim.x + threadIdx.x;       // pair index
  if (j >= 2560) return;
  int s = m & (S_ - 1);
  long rowbase = (long)m * NQKV_;
  if (j < 2048) {  // Q: element pair (2j, 2j+1) in [0,4096)
    int dpair = j & 63;
    float a = qkv[rowbase + 2 * j], bb = qkv[rowbase + 2 * j + 1];
    float c = fcos[s * 64 + dpair], si = fsin[s * 64 + dpair];
    long o = (long)m * 4096 + 2 * j;
    qb[o] = __float2bfloat16(a * c - bb * si);
    qb[o + 1] = __float2bfloat16(a * si + bb * c);
  } else {  // K: pair (4096+2j2, ...)
    int j2 = j - 2048;  // 0..511
    int kvh = j2 >> 6, dpair = j2 & 63;
    float a = qkv[rowbase + 4096 + 2 * j2], bb = qkv[rowbase + 4096 + 2 * j2 + 1];
    float c = fcos[s * 64 + dpair], si = fsin[s * 64 + dpair];
    int b = m >> 9;
    long o = (((long)(b * HKV_ + kvh)) * T_ + 512 + s) * HD_ + 2 * dpair;
    kb[o] = __float2bfloat16(a * c - bb * si);
    kb[o + 1] = __float2bfloat16(a * si + bb * c);
  }
}

// K cache part: kb[b][kvh][t][d] = bf16(cache_k[b][t][kvh][d]), t<512.
__global__ void kcache_cvt(const float* __restrict__ cache_k,
                           __hip_bfloat16* __restrict__ kb) {
  long i = (long)blockIdx.x * 256 + threadIdx.x;  // over 4*8*512*128
  if (i >= (long)B_ * HKV_ * 512 * HD_) return;
  int d = i & 127;
  int t = (i >> 7) & 511;
  int kvh = (i >> 16) & 7;
  int b = i >> 19;
  long o = (((long)(b * HKV_ + kvh)) * T_ + t) * HD_ + d;
  kb[o] = __float2bfloat16(
      cache_k[(((long)(b * 512 + t)) * HKV_ + kvh) * HD_ + d]);
}

// V assemble+transpose: vtb[b][kvh][d][t] <- cache_v (t<512) / qkv xv (t>=512).
// LDS 32x32 tile transpose for coalescing both sides. grid (32,4,32) x (32,8).
__global__ void v_transpose(const float* __restrict__ cache_v,
                            const float* __restrict__ qkv,
                            __hip_bfloat16* __restrict__ vtb) {
  __shared__ float tile[32][33];
  int t0 = blockIdx.x * 32, d0 = blockIdx.y * 32;
  int bk = blockIdx.z;
  int b = bk >> 3, kvh = bk & 7;
#pragma unroll
  for (int it = 0; it < 4; it++) {
    int t = t0 + threadIdx.y + it * 8;
    int d = d0 + threadIdx.x;
    float v;
    if (t < 512)
      v = cache_v[(((long)(b * 512 + t)) * HKV_ + kvh) * HD_ + d];
    else
      v = qkv[((long)(b * S_) + (t - 512)) * NQKV_ + 5120 + kvh * HD_ + d];
    tile[threadIdx.y + it * 8][threadIdx.x] = v;
  }
  __syncthreads();
#pragma unroll
  for (int it = 0; it < 4; it++) {
    int d = d0 + threadIdx.y + it * 8;
    int t = t0 + threadIdx.x;
    vtb[((long)bk * HD_ + d) * T_ + t] =
        __float2bfloat16(tile[threadIdx.x][threadIdx.y + it * 8]);
  }
}

// ---------------------------------------------------------------------------
// Masked softmax over score rows. One block (256 thr) per (z,q) row of T=1024.
// Valid length L = 513+q (causal, START=512). Writes bf16 P in-place over the
// score row (P row overlays the first 2KB of its own S row => race-free).
// ---------------------------------------------------------------------------
template <typename SDT>
__global__ void softmax_kernel(SDT* __restrict__ Sb,
                               __hip_bfloat16* __restrict__ Pb, long ldS,
                               long ldP) {
  int q = blockIdx.x, z = blockIdx.y;
  long srow = ((long)z * S_ + q) * ldS;
  long prow = ((long)z * S_ + q) * ldP;
  int tid = threadIdx.x;
  int L = 513 + q;
  const float scale = 0.08838834764831845f;  // 1/sqrt(128)

  float v[4];
  float m = -1e30f;
#pragma unroll
  for (int i = 0; i < 4; i++) {
    int k = tid + i * 256;
    float s = (k < L) ? ld_f(&Sb[srow + k]) * scale : -1e30f;
    v[i] = s;
    m = fmaxf(m, s);
  }
#pragma unroll
  for (int off = 32; off; off >>= 1) m = fmaxf(m, __shfl_xor(m, off));
  __shared__ float redm[4], reds[4];
  int wid = tid >> 6;
  if ((tid & 63) == 0) redm[wid] = m;
  __syncthreads();  // also: all S reads complete before in-place P writes
  m = fmaxf(fmaxf(redm[0], redm[1]), fmaxf(redm[2], redm[3]));

  float sum = 0.f, p[4];
#pragma unroll
  for (int i = 0; i < 4; i++) {
    int k = tid + i * 256;
    p[i] = (k < L) ? __expf(v[i] - m) : 0.f;
    sum += p[i];
  }
#pragma unroll
  for (int off = 32; off; off >>= 1) sum += __shfl_xor(sum, off);
  if ((tid & 63) == 0) reds[wid] = sum;
  __syncthreads();
  sum = reds[0] + reds[1] + reds[2] + reds[3];
  float inv = 1.f / sum;
#pragma unroll
  for (int i = 0; i < 4; i++) {
    int k = tid + i * 256;
    Pb[prow + k] = __float2bfloat16(p[i] * inv);
  }
}

// ---------------------------------------------------------------------------
extern "C" void kernel_launch(void* const* d_in, const int* in_sizes, int n_in,
                              void* d_out, int out_size, void* d_ws,
                              size_t ws_size, hipStream_t stream) {
  const float* x = (const float*)d_in[0];
  const float* wq = (const float*)d_in[1];
  const float* wk = (const float*)d_in[2];
  const float* wv = (const float*)d_in[3];
  const float* wo = (const float*)d_in[4];
  const float* fcos = (const float*)d_in[5];
  const float* fsin = (const float*)d_in[6];
  const float* cache_k = (const float*)d_in[7];
  const float* cache_v = (const float*)d_in[8];
  float* out = (float*)d_out;

  // ---- workspace layout (phase-aliased; stream order guarantees safety) ----
  // R0: xb (QKV-GEMM A) -> qb (rope'd Q) -> ob (attn out), all 16.8MB bf16
  // R1: wqkv bf16 (50.3MB) -> wo bf16 (33.6MB)
  // R2: qkv fp32 (50.3MB) -> scores S (268.4MB fp32 or 134.2MB bf16; P bf16
  //     packed in-place over S rows)
  // R3: kb  bf16 (b,kvh,t,d)   8.4MB
  // R4: vtb bf16 (b,kvh,d,t)   8.4MB
  char* ws = (char*)d_ws;
  const size_t szR0 = (size_t)M_ * 4096 * 2;
  const size_t szR1 = (size_t)NQKV_ * D_ * 2;
  const size_t szS_f32 = (size_t)B_ * H_ * S_ * T_ * 4;
  const size_t szKV = (size_t)B_ * HKV_ * T_ * HD_ * 2;
  const size_t base = szR0 + szR1 + 2 * szKV;
  bool sf32 = (ws_size >= base + szS_f32 + 1024);
  const size_t szR2 = sf32 ? szS_f32 : szS_f32 / 2;

  size_t R0 = 0;
  size_t R1 = R0 + szR0;
  size_t R2 = R1 + szR1;
  size_t R3 = R2 + szR2;
  size_t R4 = R3 + szKV;

  __hip_bfloat16* xb = (__hip_bfloat16*)(ws + R0);   // also qb, ob
  __hip_bfloat16* wqkvb = (__hip_bfloat16*)(ws + R1);  // also wob
  float* qkvf = (float*)(ws + R2);
  __hip_bfloat16* kb = (__hip_bfloat16*)(ws + R3);
  __hip_bfloat16* vtb = (__hip_bfloat16*)(ws + R4);

  dim3 blk(256);

  // 1) converts: x, wq|wk|wv -> bf16
  cvt_f32_bf16<<<(M_ * (long)D_ / 4 + 255) / 256, blk, 0, stream>>>(
      x, xb, (long)M_ * D_);
  cvt_f32_bf16<<<((long)D_ * D_ / 4 + 255) / 256, blk, 0, stream>>>(
      wq, wqkvb, (long)D_ * D_);
  cvt_f32_bf16<<<((long)1024 * D_ / 4 + 255) / 256, blk, 0, stream>>>(
      wk, wqkvb + (long)4096 * D_, (long)1024 * D_);
  cvt_f32_bf16<<<((long)1024 * D_ / 4 + 255) / 256, blk, 0, stream>>>(
      wv, wqkvb + (long)5120 * D_, (long)1024 * D_);

  // 2) QKV projection: qkvf[m][e] = sum_d xb[m][d] * wqkv[e][d]
  gemm_nt<float><<<dim3(NQKV_ / 128, M_ / 128, 1), blk, 0, stream>>>(
      xb, wqkvb, qkvf, M_, NQKV_, D_, D_, D_, NQKV_, 1, 1, 0, 0, 0, 0, 0, 0);

  // 3) RoPE -> qb (reuses R0; xb dead), K-new into kb
  __hip_bfloat16* qb = xb;
  rope_kernel<<<dim3(10, M_), blk, 0, stream>>>(qkvf, fcos, fsin, qb, kb);

  // 4) K cache convert, V assemble+transpose
  kcache_cvt<<<((long)B_ * HKV_ * 512 * HD_ + 255) / 256, blk, 0, stream>>>(
      cache_k, kb);
  v_transpose<<<dim3(T_ / 32, HD_ / 32, B_ * HKV_), dim3(32, 8), 0, stream>>>(
      cache_v, qkvf, vtb);

  // 5) wo -> bf16 (R1; wqkv dead after step 2, stream-ordered)
  __hip_bfloat16* wob = wqkvb;
  cvt_f32_bf16<<<((long)D_ * D_ / 4 + 255) / 256, blk, 0, stream>>>(
      wo, wob, (long)D_ * D_);

  // 6) scores: S[z][q][k] = sum_d Q[b,q,h,d] * K[b,kvh,k,d]; z=b*H+h
  long ldP = sf32 ? 2 * T_ : T_;
  if (sf32) {
    gemm_nt<float><<<dim3(T_ / 128, S_ / 128, B_ * H_), blk, 0, stream>>>(
        qb, kb, (float*)(ws + R2), S_, T_, HD_, (long)H_ * HD_, HD_, T_, H_, 4,
        (long)S_ * H_ * HD_, HD_, (long)HKV_ * T_ * HD_, (long)T_ * HD_,
        (long)H_ * S_ * T_, (long)S_ * T_);
    softmax_kernel<float><<<dim3(S_, B_ * H_), blk, 0, stream>>>(
        (float*)(ws + R2), (__hip_bfloat16*)(ws + R2), T_, ldP);
  } else {
    gemm_nt<__hip_bfloat16>
        <<<dim3(T_ / 128, S_ / 128, B_ * H_), blk, 0, stream>>>(
            qb, kb, (__hip_bfloat16*)(ws + R2), S_, T_, HD_, (long)H_ * HD_,
            HD_, T_, H_, 4, (long)S_ * H_ * HD_, HD_, (long)HKV_ * T_ * HD_,
            (long)T_ * HD_, (long)H_ * S_ * T_, (long)S_ * T_);
    softmax_kernel<__hip_bfloat16><<<dim3(S_, B_ * H_), blk, 0, stream>>>(
        (__hip_bfloat16*)(ws + R2), (__hip_bfloat16*)(ws + R2), T_, ldP);
  }

  // 7) PV: ob[b,q,h,d] = sum_k P[z][q][k] * VT[b,kvh,d,k]  (R0; qb dead)
  __hip_bfloat16* ob = xb;
  gemm_nt<__hip_bfloat16><<<dim3(HD_ / 128, S_ / 128, B_ * H_), blk, 0,
                            stream>>>(
      (const __hip_bfloat16*)(ws + R2), vtb, ob, S_, HD_, T_, ldP, T_,
      (long)H_ * HD_, H_, 4, (long)H_ * S_ * ldP, (long)S_ * ldP,
      (long)HKV_ * HD_ * T_, (long)HD_ * T_, (long)S_ * H_ * HD_, (long)HD_);

  // 8) output projection: out[m][d] = sum_e ob[m][e] * wo[d][e]
  gemm_nt<float><<<dim3(D_ / 128, M_ / 128, 1), blk, 0, stream>>>(
      ob, wob, out, M_, D_, D_, D_, D_, D_, 1, 1, 0, 0, 0, 0, 0, 0);
}

// Round 4
// 568.262 us; speedup vs baseline: 1.3088x; 1.1530x over previous
//
#include <hip/hip_runtime.h>
#include <hip/hip_bf16.h>

// ---------------------------------------------------------------------------
// Attention block, MI355X bf16-MFMA (round 4: fused flash attention replaces
// QK-GEMM + softmax + PV-GEMM; removes ~670 MB of score/P HBM round-trip).
// Shapes (hardcoded): B=4 S=512 D=4096 H=32 HKV=8 HD=128 START=512 T=1024.
// ---------------------------------------------------------------------------

#define B_ 4
#define S_ 512
#define D_ 4096
#define H_ 32
#define HKV_ 8
#define HD_ 128
#define T_ 1024
#define M_ 2048
#define NQKV_ 6144

typedef __attribute__((ext_vector_type(8))) short bf16x8;  // 8 bf16 (4 VGPRs)
typedef __attribute__((ext_vector_type(4))) float f32x4;   // MFMA C/D

#define GLOAD_LDS16(g, l)                                                     \
  __builtin_amdgcn_global_load_lds(                                           \
      (const __attribute__((address_space(1))) void*)(g),                     \
      (__attribute__((address_space(3))) void*)(l), 16, 0, 0)

__device__ __forceinline__ void st_c(float* p, float v) { *p = v; }
__device__ __forceinline__ void st_c(__hip_bfloat16* p, float v) {
  *p = __float2bfloat16(v);
}

// ---------------------------------------------------------------------------
// fp32 -> bf16 convert (vectorized float4 -> 4x bf16 packed 8B store)
// ---------------------------------------------------------------------------
__global__ void cvt_f32_bf16(const float* __restrict__ in,
                             __hip_bfloat16* __restrict__ out, long n) {
  long i = ((long)blockIdx.x * blockDim.x + threadIdx.x) * 4;
  if (i >= n) return;
  float4 v = *(const float4*)(in + i);
  __hip_bfloat16 t[4] = {__float2bfloat16(v.x), __float2bfloat16(v.y),
                         __float2bfloat16(v.z), __float2bfloat16(v.w)};
  *(uint2*)(out + i) = *(const uint2*)t;
}

// ---------------------------------------------------------------------------
// NT bf16 MFMA GEMM (round-3 version: XOR-chunk-swizzled LDS, conflict-free
// + quad-contiguous staging). Used for QKV projection and output projection.
// ---------------------------------------------------------------------------
template <typename CT>
__global__ __launch_bounds__(256) void gemm_nt(
    const __hip_bfloat16* __restrict__ A, const __hip_bfloat16* __restrict__ B,
    CT* __restrict__ C, int M, int N, int K, long ldA, long ldB, long ldC,
    int Hdiv, int rep, long sAb, long sAh, long sBb, long sBh, long sCb,
    long sCh) {
  int z = blockIdx.z;
  int zb = z / Hdiv, zh = z - zb * Hdiv;
  A += (long)zb * sAb + (long)zh * sAh;
  B += (long)zb * sBb + (long)(zh / rep) * sBh;
  C += (long)zb * sCb + (long)zh * sCh;

  const int m0 = blockIdx.y * 128;
  const int n0 = blockIdx.x * 128;
  const int tid = threadIdx.x;
  const int wave = tid >> 6, lane = tid & 63;
  const int wm = (wave >> 1) * 64, wn = (wave & 1) * 64;

  __shared__ __align__(16) __hip_bfloat16 As[128 * 32];
  __shared__ __align__(16) __hip_bfloat16 Bs[128 * 32];

  const int slot0 = tid, slot1 = 256 + tid;
  const int r0 = slot0 >> 2, c0 = (slot0 & 3) ^ ((r0 >> 1) & 3);
  const int r1 = slot1 >> 2, c1 = (slot1 & 3) ^ ((r1 >> 1) & 3);
  const __hip_bfloat16* gA0 = A + (long)(m0 + r0) * ldA + c0 * 8;
  const __hip_bfloat16* gA1 = A + (long)(m0 + r1) * ldA + c1 * 8;
  const __hip_bfloat16* gB0 = B + (long)(n0 + r0) * ldB + c0 * 8;
  const __hip_bfloat16* gB1 = B + (long)(n0 + r1) * ldB + c1 * 8;
  __hip_bfloat16* sA0 = &As[wave * 512];
  __hip_bfloat16* sA1 = &As[2048 + wave * 512];
  __hip_bfloat16* sB0 = &Bs[wave * 512];
  __hip_bfloat16* sB1 = &Bs[2048 + wave * 512];

  const int lr = lane & 15;
  const int sfrag = (lane >> 4) ^ ((lr >> 1) & 3);
  const int abase = (wm + lr) * 32 + sfrag * 8;
  const int bbase = (wn + lr) * 32 + sfrag * 8;

  f32x4 acc[4][4];
#pragma unroll
  for (int i = 0; i < 4; i++)
#pragma unroll
    for (int j = 0; j < 4; j++) acc[i][j] = f32x4{0.f, 0.f, 0.f, 0.f};

  for (int kt = 0; kt < K; kt += 32) {
    GLOAD_LDS16(gA0, sA0);
    GLOAD_LDS16(gA1, sA1);
    GLOAD_LDS16(gB0, sB0);
    GLOAD_LDS16(gB1, sB1);
    gA0 += 32;
    gA1 += 32;
    gB0 += 32;
    gB1 += 32;
    __syncthreads();

    bf16x8 af[4], bfv[4];
#pragma unroll
    for (int i = 0; i < 4; i++) {
      af[i] = *(const bf16x8*)&As[abase + i * 512];
      bfv[i] = *(const bf16x8*)&Bs[bbase + i * 512];
    }
#pragma unroll
    for (int i = 0; i < 4; i++)
#pragma unroll
      for (int j = 0; j < 4; j++)
        acc[i][j] =
            __builtin_amdgcn_mfma_f32_16x16x32_bf16(af[i], bfv[j], acc[i][j],
                                                    0, 0, 0);
    __syncthreads();
  }

  const int crow0 = m0 + wm + (lane >> 4) * 4;
  const int ccol0 = n0 + wn + (lane & 15);
#pragma unroll
  for (int i = 0; i < 4; i++)
#pragma unroll
    for (int j = 0; j < 4; j++)
#pragma unroll
      for (int r = 0; r < 4; r++)
        st_c(&C[(long)(crow0 + i * 16 + r) * ldC + (ccol0 + j * 16)],
             acc[i][j][r]);
}

// ---------------------------------------------------------------------------
// Fused flash attention. Block = (q-tile of 128 rows) x (one b,h pair).
// Grid (4, 128) x 256 threads (4 waves); wave w owns q-rows [w*32, w*32+32).
// Iterates T in tiles of 64 keys with online softmax; causal => q-tile qt
// needs ntiles = 10+2*qt of 16, last 2 masked.
//
// LDS (51.2 KB): Ks 64x128 bf16 (chunk-swizzled c^(t&7)) | Vs 128x64
// (c^(d&7)) | Ps 128 x stride-72 (pad rotates bank groups). Epilogue
// overlays an O bounce (stride 136) for coalesced stores.
// Q stays in registers (A-frags, loaded once). S/O accumulate fp32 in
// C-layout regs; row reductions = shfl_xor over 16-lane groups.
// ---------------------------------------------------------------------------
__global__ __launch_bounds__(256, 2) void flash_attn(
    const __hip_bfloat16* __restrict__ qb,   // (b,s,h,d)
    const __hip_bfloat16* __restrict__ kb,   // (b,kvh,t,d)
    const __hip_bfloat16* __restrict__ vtb,  // (b,kvh,d,t)
    __hip_bfloat16* __restrict__ ob) {       // (b,s,h,d)
  const int qt = 3 - blockIdx.x;  // heavy blocks (more tiles) first
  const int z = blockIdx.y;
  const int b = z >> 5, h = z & 31, kvh = h >> 2;
  const int q0 = qt * 128;
  const int tid = threadIdx.x, wave = tid >> 6, lane = tid & 63;
  const int lr = lane & 15, lq = lane >> 4;
  const int wrow = wave * 32;
  const float scale = 0.08838834764831845f;  // 1/sqrt(128)

  __shared__ __align__(16) __hip_bfloat16 smem[64 * 128 + 128 * 64 + 128 * 72];
  __hip_bfloat16* Ks = smem;
  __hip_bfloat16* Vs = smem + 64 * 128;
  __hip_bfloat16* Ps = smem + 64 * 128 + 128 * 64;
  __hip_bfloat16* Os = smem;  // epilogue overlay, stride 136 (17408 elems)

  const __hip_bfloat16* Kz = kb + ((long)(b * 8 + kvh)) * T_ * HD_;
  const __hip_bfloat16* Vz = vtb + ((long)(b * 8 + kvh)) * HD_ * T_;
  const __hip_bfloat16* Qz = qb + ((long)(b * 512 + q0)) * 4096 + h * 128;
  __hip_bfloat16* obz = ob + ((long)(b * 512 + q0)) * 4096 + h * 128;

  // Q fragments: A[m = i*16+lr][k = kb4*32 + lq*8], rows relative to wrow.
  bf16x8 qf[2][4];
#pragma unroll
  for (int i = 0; i < 2; i++)
#pragma unroll
    for (int kb4 = 0; kb4 < 4; kb4++)
      qf[i][kb4] = *(const bf16x8*)(Qz + (long)(wrow + i * 16 + lr) * 4096 +
                                    kb4 * 32 + lq * 8);

  // staging source offsets (element units). K: G=it*256+tid -> t=G>>4,
  // c=(G&15)^(t&7). V: d=G>>3, c=(G&7)^(d&7). Quad-contiguous (XOR permutes
  // within a 64B block), reads land 2-way (free).
  int kOff[4], vOff[4];
#pragma unroll
  for (int it = 0; it < 4; it++) {
    int G = it * 256 + tid;
    int t = G >> 4, ck = (G & 15) ^ (t & 7);
    kOff[it] = t * 128 + ck * 8;
    int d = G >> 3, cv = (G & 7) ^ (d & 7);
    vOff[it] = d * 1024 + cv * 8;
  }

  f32x4 O[2][8];
#pragma unroll
  for (int i = 0; i < 2; i++)
#pragma unroll
    for (int j = 0; j < 8; j++) O[i][j] = f32x4{0.f, 0.f, 0.f, 0.f};
  float mst[2][4], lst[2][4];
#pragma unroll
  for (int i = 0; i < 2; i++)
#pragma unroll
    for (int r = 0; r < 4; r++) {
      mst[i][r] = -1e30f;
      lst[i][r] = 0.f;
    }

  const int ntiles = 10 + 2 * qt, fulltiles = 8 + 2 * qt;
  const int hxor = lr & 7;  // (t&7)==(d&7)==lr&7 for frag rows j*16+lr

  for (int kt = 0; kt < ntiles; kt++) {
    const int k0 = kt * 64;
#pragma unroll
    for (int it = 0; it < 4; it++)
      GLOAD_LDS16(Kz + (long)k0 * 128 + kOff[it],
                  Ks + (it * 256 + wave * 64) * 8);
#pragma unroll
    for (int it = 0; it < 4; it++)
      GLOAD_LDS16(Vz + k0 + vOff[it], Vs + (it * 256 + wave * 64) * 8);
    __syncthreads();

    // ---- QK^T: S[32 x 64] per wave ----
    f32x4 s[2][4];
#pragma unroll
    for (int i = 0; i < 2; i++)
#pragma unroll
      for (int j = 0; j < 4; j++) s[i][j] = f32x4{0.f, 0.f, 0.f, 0.f};
#pragma unroll
    for (int kb4 = 0; kb4 < 4; kb4++) {
      bf16x8 kf[4];
#pragma unroll
      for (int j = 0; j < 4; j++)
        kf[j] = *(const bf16x8*)(Ks + (j * 16 + lr) * 128 +
                                 ((kb4 * 4 + lq) ^ hxor) * 8);
#pragma unroll
      for (int i = 0; i < 2; i++)
#pragma unroll
        for (int j = 0; j < 4; j++)
          s[i][j] = __builtin_amdgcn_mfma_f32_16x16x32_bf16(qf[i][kb4], kf[j],
                                                            s[i][j], 0, 0, 0);
    }

    // ---- scale + causal mask (boundary tiles only) ----
    const bool mt = (kt >= fulltiles);
#pragma unroll
    for (int i = 0; i < 2; i++)
#pragma unroll
      for (int j = 0; j < 4; j++)
#pragma unroll
        for (int r = 0; r < 4; r++) {
          float sv = s[i][j][r] * scale;
          if (mt) {
            int key = k0 + j * 16 + lr;
            int qp = 512 + q0 + wrow + i * 16 + lq * 4 + r;
            if (key > qp) sv = -1e30f;
          }
          s[i][j][r] = sv;
        }

    // ---- online softmax update ----
    float al[2][4];
#pragma unroll
    for (int i = 0; i < 2; i++)
#pragma unroll
      for (int r = 0; r < 4; r++) {
        float mx = fmaxf(fmaxf(s[i][0][r], s[i][1][r]),
                         fmaxf(s[i][2][r], s[i][3][r]));
        mx = fmaxf(mx, __shfl_xor(mx, 1));
        mx = fmaxf(mx, __shfl_xor(mx, 2));
        mx = fmaxf(mx, __shfl_xor(mx, 4));
        mx = fmaxf(mx, __shfl_xor(mx, 8));
        float mn = fmaxf(mst[i][r], mx);
        al[i][r] = __expf(mst[i][r] - mn);
        mst[i][r] = mn;
      }
#pragma unroll
    for (int i = 0; i < 2; i++)
#pragma unroll
      for (int j = 0; j < 4; j++)
#pragma unroll
        for (int r = 0; r < 4; r++)
          s[i][j][r] = __expf(s[i][j][r] - mst[i][r]);
#pragma unroll
    for (int i = 0; i < 2; i++)
#pragma unroll
      for (int r = 0; r < 4; r++) {
        float sm = s[i][0][r] + s[i][1][r] + s[i][2][r] + s[i][3][r];
        sm += __shfl_xor(sm, 1);
        sm += __shfl_xor(sm, 2);
        sm += __shfl_xor(sm, 4);
        sm += __shfl_xor(sm, 8);
        lst[i][r] = lst[i][r] * al[i][r] + sm;
      }
#pragma unroll
    for (int i = 0; i < 2; i++)
#pragma unroll
      for (int j = 0; j < 8; j++)
#pragma unroll
        for (int r = 0; r < 4; r++) O[i][j][r] *= al[i][r];

    // ---- P -> LDS (bf16, C-layout scatter; pad-72 rotates bank groups) ----
#pragma unroll
    for (int i = 0; i < 2; i++)
#pragma unroll
      for (int j = 0; j < 4; j++)
#pragma unroll
        for (int r = 0; r < 4; r++)
          Ps[(wrow + i * 16 + lq * 4 + r) * 72 + j * 16 + lr] =
              __float2bfloat16(s[i][j][r]);

    // ---- PV: O += P * V^T ----
#pragma unroll
    for (int kc = 0; kc < 2; kc++) {
      bf16x8 pa[2];
#pragma unroll
      for (int i = 0; i < 2; i++)
        pa[i] = *(const bf16x8*)(Ps + (wrow + i * 16 + lr) * 72 + kc * 32 +
                                 lq * 8);
      bf16x8 vf[8];
#pragma unroll
      for (int j = 0; j < 8; j++)
        vf[j] = *(const bf16x8*)(Vs + (j * 16 + lr) * 64 +
                                 ((kc * 4 + lq) ^ hxor) * 8);
#pragma unroll
      for (int i = 0; i < 2; i++)
#pragma unroll
        for (int j = 0; j < 8; j++)
          O[i][j] = __builtin_amdgcn_mfma_f32_16x16x32_bf16(pa[i], vf[j],
                                                            O[i][j], 0, 0, 0);
    }
    __syncthreads();
  }

  // ---- epilogue: normalize, LDS bounce, coalesced store ----
#pragma unroll
  for (int i = 0; i < 2; i++)
#pragma unroll
    for (int r = 0; r < 4; r++) {
      float inv = 1.f / lst[i][r];
#pragma unroll
      for (int j = 0; j < 8; j++)
        Os[(wrow + i * 16 + lq * 4 + r) * 136 + j * 16 + lr] =
            __float2bfloat16(O[i][j][r] * inv);
    }
  __syncthreads();
#pragma unroll
  for (int it = 0; it < 8; it++) {
    int G = it * 256 + tid;
    int m = G >> 4, c = G & 15;
    *(bf16x8*)(obz + (long)m * 4096 + c * 8) =
        *(const bf16x8*)(Os + m * 136 + c * 8);
  }
}

// ---------------------------------------------------------------------------
// RoPE on Q and K-new (reads fp32 qkv, writes bf16 q (b,s,h,d) and bf16 K-new
// into assembled K (b,kvh,512+s,d)).
// ---------------------------------------------------------------------------
__global__ void rope_kernel(const float* __restrict__ qkv,
                            const float* __restrict__ fcos,
                            const float* __restrict__ fsin,
                            __hip_bfloat16* __restrict__ qb,
                            __hip_bfloat16* __restrict__ kb) {
  int m = blockIdx.y;
  int j = blockIdx.x * blockDim.x + threadIdx.x;
  if (j >= 2560) return;
  int s = m & (S_ - 1);
  long rowbase = (long)m * NQKV_;
  if (j < 2048) {
    int dpair = j & 63;
    float a = qkv[rowbase + 2 * j], bb = qkv[rowbase + 2 * j + 1];
    float c = fcos[s * 64 + dpair], si = fsin[s * 64 + dpair];
    long o = (long)m * 4096 + 2 * j;
    qb[o] = __float2bfloat16(a * c - bb * si);
    qb[o + 1] = __float2bfloat16(a * si + bb * c);
  } else {
    int j2 = j - 2048;
    int kvh = j2 >> 6, dpair = j2 & 63;
    float a = qkv[rowbase + 4096 + 2 * j2], bb = qkv[rowbase + 4096 + 2 * j2 + 1];
    float c = fcos[s * 64 + dpair], si = fsin[s * 64 + dpair];
    int b = m >> 9;
    long o = (((long)(b * HKV_ + kvh)) * T_ + 512 + s) * HD_ + 2 * dpair;
    kb[o] = __float2bfloat16(a * c - bb * si);
    kb[o + 1] = __float2bfloat16(a * si + bb * c);
  }
}

// K cache part: kb[b][kvh][t][d] = bf16(cache_k[b][t][kvh][d]), t<512.
__global__ void kcache_cvt(const float* __restrict__ cache_k,
                           __hip_bfloat16* __restrict__ kb) {
  long i = (long)blockIdx.x * 256 + threadIdx.x;
  if (i >= (long)B_ * HKV_ * 512 * HD_) return;
  int d = i & 127;
  int t = (i >> 7) & 511;
  int kvh = (i >> 16) & 7;
  int b = i >> 19;
  long o = (((long)(b * HKV_ + kvh)) * T_ + t) * HD_ + d;
  kb[o] = __float2bfloat16(
      cache_k[(((long)(b * 512 + t)) * HKV_ + kvh) * HD_ + d]);
}

// V assemble+transpose: vtb[b][kvh][d][t] <- cache_v (t<512) / qkv xv (t>=512).
__global__ void v_transpose(const float* __restrict__ cache_v,
                            const float* __restrict__ qkv,
                            __hip_bfloat16* __restrict__ vtb) {
  __shared__ float tile[32][33];
  int t0 = blockIdx.x * 32, d0 = blockIdx.y * 32;
  int bk = blockIdx.z;
  int b = bk >> 3, kvh = bk & 7;
#pragma unroll
  for (int it = 0; it < 4; it++) {
    int t = t0 + threadIdx.y + it * 8;
    int d = d0 + threadIdx.x;
    float v;
    if (t < 512)
      v = cache_v[(((long)(b * 512 + t)) * HKV_ + kvh) * HD_ + d];
    else
      v = qkv[((long)(b * S_) + (t - 512)) * NQKV_ + 5120 + kvh * HD_ + d];
    tile[threadIdx.y + it * 8][threadIdx.x] = v;
  }
  __syncthreads();
#pragma unroll
  for (int it = 0; it < 4; it++) {
    int d = d0 + threadIdx.y + it * 8;
    int t = t0 + threadIdx.x;
    vtb[((long)bk * HD_ + d) * T_ + t] =
        __float2bfloat16(tile[threadIdx.x][threadIdx.y + it * 8]);
  }
}

// ---------------------------------------------------------------------------
extern "C" void kernel_launch(void* const* d_in, const int* in_sizes, int n_in,
                              void* d_out, int out_size, void* d_ws,
                              size_t ws_size, hipStream_t stream) {
  const float* x = (const float*)d_in[0];
  const float* wq = (const float*)d_in[1];
  const float* wk = (const float*)d_in[2];
  const float* wv = (const float*)d_in[3];
  const float* wo = (const float*)d_in[4];
  const float* fcos = (const float*)d_in[5];
  const float* fsin = (const float*)d_in[6];
  const float* cache_k = (const float*)d_in[7];
  const float* cache_v = (const float*)d_in[8];
  float* out = (float*)d_out;

  // ---- workspace layout (phase-aliased; stream order guarantees safety) ----
  // R0: xb -> qb (rope'd Q) -> ob (flash out; safe alias: each flash block
  //     reads exactly the Q region it later overwrites, Q->regs first)
  // R1: wqkv bf16 -> wo bf16 | R2: qkv fp32 | R3: kb | R4: vtb
  char* ws = (char*)d_ws;
  const size_t szR0 = (size_t)M_ * 4096 * 2;
  const size_t szR1 = (size_t)NQKV_ * D_ * 2;
  const size_t szR2 = (size_t)M_ * NQKV_ * 4;
  const size_t szKV = (size_t)B_ * HKV_ * T_ * HD_ * 2;

  size_t R0 = 0;
  size_t R1 = R0 + szR0;
  size_t R2 = R1 + szR1;
  size_t R3 = R2 + szR2;
  size_t R4 = R3 + szKV;

  __hip_bfloat16* xb = (__hip_bfloat16*)(ws + R0);     // also qb, ob
  __hip_bfloat16* wqkvb = (__hip_bfloat16*)(ws + R1);  // also wob
  float* qkvf = (float*)(ws + R2);
  __hip_bfloat16* kb = (__hip_bfloat16*)(ws + R3);
  __hip_bfloat16* vtb = (__hip_bfloat16*)(ws + R4);

  dim3 blk(256);

  // 1) converts
  cvt_f32_bf16<<<(M_ * (long)D_ / 4 + 255) / 256, blk, 0, stream>>>(
      x, xb, (long)M_ * D_);
  cvt_f32_bf16<<<((long)D_ * D_ / 4 + 255) / 256, blk, 0, stream>>>(
      wq, wqkvb, (long)D_ * D_);
  cvt_f32_bf16<<<((long)1024 * D_ / 4 + 255) / 256, blk, 0, stream>>>(
      wk, wqkvb + (long)4096 * D_, (long)1024 * D_);
  cvt_f32_bf16<<<((long)1024 * D_ / 4 + 255) / 256, blk, 0, stream>>>(
      wv, wqkvb + (long)5120 * D_, (long)1024 * D_);

  // 2) QKV projection
  gemm_nt<float><<<dim3(NQKV_ / 128, M_ / 128, 1), blk, 0, stream>>>(
      xb, wqkvb, qkvf, M_, NQKV_, D_, D_, D_, NQKV_, 1, 1, 0, 0, 0, 0, 0, 0);

  // 3) RoPE -> qb (R0 reuse), K-new into kb
  __hip_bfloat16* qb = xb;
  rope_kernel<<<dim3(10, M_), blk, 0, stream>>>(qkvf, fcos, fsin, qb, kb);

  // 4) K cache convert, V assemble+transpose
  kcache_cvt<<<((long)B_ * HKV_ * 512 * HD_ + 255) / 256, blk, 0, stream>>>(
      cache_k, kb);
  v_transpose<<<dim3(T_ / 32, HD_ / 32, B_ * HKV_), dim3(32, 8), 0, stream>>>(
      cache_v, qkvf, vtb);

  // 5) wo -> bf16 (R1 reuse)
  __hip_bfloat16* wob = wqkvb;
  cvt_f32_bf16<<<((long)D_ * D_ / 4 + 255) / 256, blk, 0, stream>>>(
      wo, wob, (long)D_ * D_);

  // 6) fused flash attention: qb -> ob (in-place over R0, block-disjoint)
  __hip_bfloat16* ob = xb;
  flash_attn<<<dim3(4, B_ * H_), blk, 0, stream>>>(qb, kb, vtb, ob);

  // 7) output projection
  gemm_nt<float><<<dim3(D_ / 128, M_ / 128, 1), blk, 0, stream>>>(
      ob, wob, out, M_, D_, D_, D_, D_, D_, 1, 1, 0, 0, 0, 0, 0, 0);
}